// Round 8
// baseline (604.435 us; speedup 1.0000x reference)
//
#include <hip/hip_runtime.h>
#include <math.h>

#define T_    4
#define B_    32
#define C_    64
#define CO_   64
#define N_    4096
#define K_    8
#define PL_   3
#define TB_   128          // T_*B_
#define TN_   256          // n-tile per conv block
#define NT_   16           // N_/TN_
#define NBLK_ 2048         // TB_*NT_
#define CCH_  32           // ci chunk staged in LDS at a time (R8: 32 -> 2 chunks, 4 barriers)

typedef float v2f __attribute__((ext_vector_type(2)));
typedef float v4f __attribute__((ext_vector_type(4)));

// ---------------------------------------------------------------------------
// Kernel 0: repack weights into co-pairs (R2 verbatim). Required: the packed
// conv codegen (wpk + pk-fma) eliminates LDS bank conflicts (1.2e5 vs 4.0e7
// scalar -- rounds 2/4/7 vs 1/3/6) and ~40us of VALU time.
// ---------------------------------------------------------------------------
__global__ __launch_bounds__(256)
void pack_w_kernel(const float* __restrict__ w, v2f* __restrict__ wpk)
{
    int i = blockIdx.x * 256 + threadIdx.x;      // p*512 + ci*8 + k
    if (i < 32 * C_ * K_) {
        int p = i >> 9;
        int r = i & 511;
        v2f v = { w[(size_t)(2 * p) * (C_ * K_) + r],
                  w[(size_t)(2 * p + 1) * (C_ * K_) + r] };
        wpk[i] = v;
    }
}

// ---------------------------------------------------------------------------
// Kernel 1: conv + BN partials. R2/R4/R7 packed inner loop VERBATIM (fragile:
// R3 live-reg prefetch and R6 scalar weights both regressed). Round-8 change
// is ONLY CCH 16->32: 2 chunks instead of 4 halves the __syncthreads count
// (8->4) attacking the ~87us barrier-drain idle. FMA chain per (co,n) is ci
// ascending, k ascending -- bitwise-identical output to all prior rounds.
// ---------------------------------------------------------------------------
__global__ __launch_bounds__(256, 4)
void conv_stats_kernel(const float* __restrict__ x, const v2f* __restrict__ wpk,
                       float* __restrict__ y, float* __restrict__ psum)
{
    __shared__ float xs[CCH_][TN_ + 8];   // 32 x 264 floats = 33.8 KB (4 blocks/CU)

    const int bx   = blockIdx.x;
    const int tb   = bx >> 4;           // 0..127
    const int n0   = (bx & 15) * TN_;   // n tile origin
    const int tid  = threadIdx.x;
    const int lane = tid & 63;
    const int wv   = __builtin_amdgcn_readfirstlane(tid >> 6);
    const int cg   = wv * 16;           // wave's co base
    const int pg0  = wv * 8;            // wave's co-pair base
    const int noff = lane * 4;          // lane's n offset inside tile

    v2f acc[8][4];                      // [co-pair][n] packed over co
#pragma unroll
    for (int p = 0; p < 8; ++p)
#pragma unroll
        for (int j = 0; j < 4; ++j) acc[p][j] = v2f{0.0f, 0.0f};

    const float* xrow = x + (size_t)tb * C_ * N_;

    for (int cc = 0; cc < C_ / CCH_; ++cc) {
        __syncthreads();   // protect xs reuse between chunks
        // stage x[tb, cc*32 .. +31, n0-3 .. n0+259] with zero padding
        for (int idx = tid; idx < CCH_ * (TN_ + 7); idx += 256) {
            int ci = idx / (TN_ + 7);
            int i  = idx - ci * (TN_ + 7);
            int n  = n0 - PL_ + i;
            float v = 0.0f;
            if (n >= 0 && n < N_) v = xrow[(size_t)(cc * CCH_ + ci) * N_ + n];
            xs[ci][i] = v;
        }
        __syncthreads();

        for (int ci2 = 0; ci2 < CCH_; ++ci2) {
            const int ci = cc * CCH_ + ci2;
            const float4* xp = (const float4*)(&xs[ci2][noff]);
            float4 xa = xp[0], xb = xp[1], xc = xp[2];
            float xr[12] = {xa.x, xa.y, xa.z, xa.w,
                            xb.x, xb.y, xb.z, xb.w,
                            xc.x, xc.y, xc.z, xc.w};
#pragma unroll
            for (int p = 0; p < 8; ++p) {
                // wave-uniform address -> s_load_dwordx2 (x4/x8 merged)
                const v2f* wq = wpk + ((size_t)(pg0 + p) * C_ + ci) * K_;
#pragma unroll
                for (int k = 0; k < K_; ++k) {
                    const v2f wv2 = wq[k];
#pragma unroll
                    for (int j = 0; j < 4; ++j) {
                        v2f xv = { xr[k + j], xr[k + j] };   // splat
                        acc[p][j] = __builtin_elementwise_fma(wv2, xv, acc[p][j]);
                    }
                }
            }
        }
    }

    // write y + per-wave BN partials (deterministic: fixed reduction order)
    float* yrow = y + (size_t)tb * CO_ * N_;
    const int nbase = n0 + noff;
#pragma unroll
    for (int p = 0; p < 8; ++p) {
        const int co0 = cg + 2 * p;
#pragma unroll
        for (int h = 0; h < 2; ++h) {
            float4 v;
            if (h == 0) v = make_float4(acc[p][0].x, acc[p][1].x, acc[p][2].x, acc[p][3].x);
            else        v = make_float4(acc[p][0].y, acc[p][1].y, acc[p][2].y, acc[p][3].y);
            const int co = co0 + h;
            *(float4*)(&yrow[(size_t)co * N_ + nbase]) = v;
            float s1 = (v.x + v.y) + (v.z + v.w);
            float s2 = (v.x * v.x + v.y * v.y) + (v.z * v.z + v.w * v.w);
#pragma unroll
            for (int off = 32; off > 0; off >>= 1) {
                s1 += __shfl_down(s1, off);
                s2 += __shfl_down(s2, off);
            }
            if (lane == 0) {
                psum[(size_t)(co * 2 + 0) * NBLK_ + bx] = s1;
                psum[(size_t)(co * 2 + 1) * NBLK_ + bx] = s2;
            }
        }
    }
}

// ---------------------------------------------------------------------------
// Kernel 2: fused BN-stats + normalize + 4-step LIF. R6's winning flat shape
// (2048 blocks x 256 thr, 4 iters/thread, nt stores) with the channel
// block-uniform: f>>10 == blockIdx>>2 for all tid, so each block redundantly
// reduces ITS channel's psum with the bitwise-identical fp64 order of the old
// stats_kernel (identical in every block -> determinism preserved, proven R3).
// Saves one graph node + gap.
// ---------------------------------------------------------------------------
#define NQ4_   2097152     // B_*CO_*N_/4 : float4 elements per timestep
#define NTHR_  524288      // 2048 blocks * 256 threads

__global__ __launch_bounds__(256)
void lif_kernel(const float* __restrict__ y, const float* __restrict__ psum,
                const float* __restrict__ gamma, const float* __restrict__ beta,
                float* __restrict__ out)
{
    __shared__ double red[256];
    __shared__ float ssf[2];

    const int bx  = blockIdx.x;
    const int tid = threadIdx.x;
    const int c   = (bx >> 2) & 63;     // block-uniform channel

    // ---- per-channel stats (bitwise-identical order to old stats_kernel) ----
    double s1 = 0.0, s2 = 0.0;
    for (int i = tid; i < NBLK_; i += 256) {
        s1 += (double)psum[(size_t)(c * 2 + 0) * NBLK_ + i];
        s2 += (double)psum[(size_t)(c * 2 + 1) * NBLK_ + i];
    }
    red[tid] = s1;
    __syncthreads();
    for (int st = 128; st > 0; st >>= 1) {
        if (tid < st) red[tid] += red[tid + st];
        __syncthreads();
    }
    const double S1 = red[0];
    __syncthreads();
    red[tid] = s2;
    __syncthreads();
    for (int st = 128; st > 0; st >>= 1) {
        if (tid < st) red[tid] += red[tid + st];
        __syncthreads();
    }
    const double S2 = red[0];

    if (tid == 0) {
        const double M    = (double)TB_ * (double)N_;
        const double mean = S1 / M;
        const double var  = S2 / M - mean * mean;
        const double inv  = 1.0 / sqrt(var + 1e-5);
        const double g    = (double)gamma[c];
        ssf[0] = (float)(g * inv);
        ssf[1] = (float)((double)beta[c] - mean * g * inv);
    }
    __syncthreads();
    const float scale = ssf[0];
    const float shift = ssf[1];

    // ---- LIF, R6 shape: flat float4 grid-stride, nt stores ----
    const int f = bx * 256 + tid;
    const v4f* y4   = (const v4f*)y;
    v4f*       out4 = (v4f*)out;

    for (int i = f; i < NQ4_; i += NTHR_) {
        v4f yv[4];
#pragma unroll
        for (int t = 0; t < 4; ++t)
            yv[t] = y4[i + t * NQ4_];

        float yin[4][4] = {{yv[0].x, yv[0].y, yv[0].z, yv[0].w},
                           {yv[1].x, yv[1].y, yv[1].z, yv[1].w},
                           {yv[2].x, yv[2].y, yv[2].z, yv[2].w},
                           {yv[3].x, yv[3].y, yv[3].z, yv[3].w}};
        float so[4][4];
#pragma unroll
        for (int e = 0; e < 4; ++e) {
            float v = 0.0f;
#pragma unroll
            for (int t = 0; t < 4; ++t) {
                const float yn = fmaf(yin[t][e], scale, shift);  // BN affine
                v = v + (yn - v) * 0.5f;                          // charge
                const float s = (v >= 1.0f) ? 1.0f : 0.0f;        // fire
                so[t][e] = s;
                v = (s != 0.0f) ? 0.0f : v;                       // hard reset
            }
        }
#pragma unroll
        for (int t = 0; t < 4; ++t) {
            v4f o = { so[t][0], so[t][1], so[t][2], so[t][3] };
            __builtin_nontemporal_store(o, &out4[i + t * NQ4_]);
        }
    }
}

// ---------------------------------------------------------------------------
extern "C" void kernel_launch(void* const* d_in, const int* in_sizes, int n_in,
                              void* d_out, int out_size, void* d_ws, size_t ws_size,
                              hipStream_t stream)
{
    const float* x     = (const float*)d_in[0];   // [4,32,64,4096]
    const float* w     = (const float*)d_in[1];   // [64,64,8]
    // d_in[2] = conv_b: cancels in BN, unused
    const float* gamma = (const float*)d_in[3];   // [64]
    const float* beta  = (const float*)d_in[4];   // [64]
    float* out = (float*)d_out;

    char* ws = (char*)d_ws;
    const size_t y_bytes    = (size_t)TB_ * CO_ * N_ * sizeof(float);   // 128 MB
    const size_t psum_bytes = (size_t)CO_ * 2 * NBLK_ * sizeof(float);  // 1 MB
    float* y    = (float*)ws;
    float* psum = (float*)(ws + y_bytes);
    v2f*   wpk  = (v2f*)(ws + y_bytes + psum_bytes);

    pack_w_kernel<<<64, 256, 0, stream>>>(w, wpk);
    conv_stats_kernel<<<NBLK_, 256, 0, stream>>>(x, wpk, y, psum);
    lif_kernel<<<NBLK_, 256, 0, stream>>>(y, psum, gamma, beta, out);
}

// Round 9
// 532.162 us; speedup vs baseline: 1.1358x; 1.1358x over previous
//
#include <hip/hip_runtime.h>
#include <math.h>

#define T_    4
#define B_    32
#define C_    64
#define CO_   64
#define N_    4096
#define K_    8
#define PL_   3
#define TB_   128          // T_*B_
#define TN_   256          // n-tile per conv block
#define NT_   16           // N_/TN_
#define NBLK_ 2048         // TB_*NT_
#define CCH_  16           // ci chunk staged in LDS (16 is the proven optimum; 32 regressed R8)

typedef float v2f __attribute__((ext_vector_type(2)));
typedef float v4f __attribute__((ext_vector_type(4)));

// ---------------------------------------------------------------------------
// Kernel 0: repack weights into co-pairs (R2 verbatim). Required: the packed
// conv codegen (wpk + pk-fma) eliminates LDS bank conflicts (1.2e5 vs 4.0e7
// scalar -- rounds 2/4/7 vs 1/3/6) and ~40us of VALU time.
// ---------------------------------------------------------------------------
__global__ __launch_bounds__(256)
void pack_w_kernel(const float* __restrict__ w, v2f* __restrict__ wpk)
{
    int i = blockIdx.x * 256 + threadIdx.x;      // p*512 + ci*8 + k
    if (i < 32 * C_ * K_) {
        int p = i >> 9;
        int r = i & 511;
        v2f v = { w[(size_t)(2 * p) * (C_ * K_) + r],
                  w[(size_t)(2 * p + 1) * (C_ * K_) + r] };
        wpk[i] = v;
    }
}

// ---------------------------------------------------------------------------
// Kernel 1: conv + BN partials — VERBATIM round-2/4/7 version (362-371 us,
// absmax 0.0, VALUBusy 76%, conflicts 1.2e5, VGPR 44, CCH=16). Fragile local
// optimum: R3 (live prefetch regs), R6 (scalar weights), R8 (CCH=32) all
// regressed it. Do not touch anything in this kernel.
// ---------------------------------------------------------------------------
__global__ __launch_bounds__(256, 4)
void conv_stats_kernel(const float* __restrict__ x, const v2f* __restrict__ wpk,
                       float* __restrict__ y, float* __restrict__ psum)
{
    __shared__ float xs[CCH_][TN_ + 8];   // 16 x 264 floats = 16.9 KB

    const int bx   = blockIdx.x;
    const int tb   = bx >> 4;           // 0..127
    const int n0   = (bx & 15) * TN_;   // n tile origin
    const int tid  = threadIdx.x;
    const int lane = tid & 63;
    const int wv   = __builtin_amdgcn_readfirstlane(tid >> 6);
    const int cg   = wv * 16;           // wave's co base
    const int pg0  = wv * 8;            // wave's co-pair base
    const int noff = lane * 4;          // lane's n offset inside tile

    v2f acc[8][4];                      // [co-pair][n] packed over co
#pragma unroll
    for (int p = 0; p < 8; ++p)
#pragma unroll
        for (int j = 0; j < 4; ++j) acc[p][j] = v2f{0.0f, 0.0f};

    const float* xrow = x + (size_t)tb * C_ * N_;

    for (int cc = 0; cc < C_ / CCH_; ++cc) {
        __syncthreads();   // protect xs reuse between chunks
        // stage x[tb, cc*16 .. +15, n0-3 .. n0+259] with zero padding
        for (int idx = tid; idx < CCH_ * (TN_ + 7); idx += 256) {
            int ci = idx / (TN_ + 7);
            int i  = idx - ci * (TN_ + 7);
            int n  = n0 - PL_ + i;
            float v = 0.0f;
            if (n >= 0 && n < N_) v = xrow[(size_t)(cc * CCH_ + ci) * N_ + n];
            xs[ci][i] = v;
        }
        __syncthreads();

        for (int ci2 = 0; ci2 < CCH_; ++ci2) {
            const int ci = cc * CCH_ + ci2;
            const float4* xp = (const float4*)(&xs[ci2][noff]);
            float4 xa = xp[0], xb = xp[1], xc = xp[2];
            float xr[12] = {xa.x, xa.y, xa.z, xa.w,
                            xb.x, xb.y, xb.z, xb.w,
                            xc.x, xc.y, xc.z, xc.w};
#pragma unroll
            for (int p = 0; p < 8; ++p) {
                // wave-uniform address -> s_load_dwordx2 (x4/x8 merged)
                const v2f* wq = wpk + ((size_t)(pg0 + p) * C_ + ci) * K_;
#pragma unroll
                for (int k = 0; k < K_; ++k) {
                    const v2f wv2 = wq[k];
#pragma unroll
                    for (int j = 0; j < 4; ++j) {
                        v2f xv = { xr[k + j], xr[k + j] };   // splat
                        acc[p][j] = __builtin_elementwise_fma(wv2, xv, acc[p][j]);
                    }
                }
            }
        }
    }

    // write y + per-wave BN partials (deterministic: fixed reduction order)
    float* yrow = y + (size_t)tb * CO_ * N_;
    const int nbase = n0 + noff;
#pragma unroll
    for (int p = 0; p < 8; ++p) {
        const int co0 = cg + 2 * p;
#pragma unroll
        for (int h = 0; h < 2; ++h) {
            float4 v;
            if (h == 0) v = make_float4(acc[p][0].x, acc[p][1].x, acc[p][2].x, acc[p][3].x);
            else        v = make_float4(acc[p][0].y, acc[p][1].y, acc[p][2].y, acc[p][3].y);
            const int co = co0 + h;
            *(float4*)(&yrow[(size_t)co * N_ + nbase]) = v;
            float s1 = (v.x + v.y) + (v.z + v.w);
            float s2 = (v.x * v.x + v.y * v.y) + (v.z * v.z + v.w * v.w);
#pragma unroll
            for (int off = 32; off > 0; off >>= 1) {
                s1 += __shfl_down(s1, off);
                s2 += __shfl_down(s2, off);
            }
            if (lane == 0) {
                psum[(size_t)(co * 2 + 0) * NBLK_ + bx] = s1;
                psum[(size_t)(co * 2 + 1) * NBLK_ + bx] = s2;
            }
        }
    }
}

// ---------------------------------------------------------------------------
// Kernel 2: fused BN-stats + normalize + 4-step LIF (R8 verbatim). 2048
// blocks x 256 thr; channel block-uniform (f>>10 == bx>>2); each block
// redundantly reduces its channel's psum with the bitwise-identical fp64
// order (identical in every block -> determinism preserved), then flat
// float4 grid-stride LIF with nontemporal stores.
// ---------------------------------------------------------------------------
#define NQ4_   2097152     // B_*CO_*N_/4 : float4 elements per timestep
#define NTHR_  524288      // 2048 blocks * 256 threads

__global__ __launch_bounds__(256)
void lif_kernel(const float* __restrict__ y, const float* __restrict__ psum,
                const float* __restrict__ gamma, const float* __restrict__ beta,
                float* __restrict__ out)
{
    __shared__ double red[256];
    __shared__ float ssf[2];

    const int bx  = blockIdx.x;
    const int tid = threadIdx.x;
    const int c   = (bx >> 2) & 63;     // block-uniform channel

    // ---- per-channel stats (bitwise-identical order to old stats_kernel) ----
    double s1 = 0.0, s2 = 0.0;
    for (int i = tid; i < NBLK_; i += 256) {
        s1 += (double)psum[(size_t)(c * 2 + 0) * NBLK_ + i];
        s2 += (double)psum[(size_t)(c * 2 + 1) * NBLK_ + i];
    }
    red[tid] = s1;
    __syncthreads();
    for (int st = 128; st > 0; st >>= 1) {
        if (tid < st) red[tid] += red[tid + st];
        __syncthreads();
    }
    const double S1 = red[0];
    __syncthreads();
    red[tid] = s2;
    __syncthreads();
    for (int st = 128; st > 0; st >>= 1) {
        if (tid < st) red[tid] += red[tid + st];
        __syncthreads();
    }
    const double S2 = red[0];

    if (tid == 0) {
        const double M    = (double)TB_ * (double)N_;
        const double mean = S1 / M;
        const double var  = S2 / M - mean * mean;
        const double inv  = 1.0 / sqrt(var + 1e-5);
        const double g    = (double)gamma[c];
        ssf[0] = (float)(g * inv);
        ssf[1] = (float)((double)beta[c] - mean * g * inv);
    }
    __syncthreads();
    const float scale = ssf[0];
    const float shift = ssf[1];

    // ---- LIF, flat float4 grid-stride, nt stores ----
    const int f = bx * 256 + tid;
    const v4f* y4   = (const v4f*)y;
    v4f*       out4 = (v4f*)out;

    for (int i = f; i < NQ4_; i += NTHR_) {
        v4f yv[4];
#pragma unroll
        for (int t = 0; t < 4; ++t)
            yv[t] = y4[i + t * NQ4_];

        float yin[4][4] = {{yv[0].x, yv[0].y, yv[0].z, yv[0].w},
                           {yv[1].x, yv[1].y, yv[1].z, yv[1].w},
                           {yv[2].x, yv[2].y, yv[2].z, yv[2].w},
                           {yv[3].x, yv[3].y, yv[3].z, yv[3].w}};
        float so[4][4];
#pragma unroll
        for (int e = 0; e < 4; ++e) {
            float v = 0.0f;
#pragma unroll
            for (int t = 0; t < 4; ++t) {
                const float yn = fmaf(yin[t][e], scale, shift);  // BN affine
                v = v + (yn - v) * 0.5f;                          // charge
                const float s = (v >= 1.0f) ? 1.0f : 0.0f;        // fire
                so[t][e] = s;
                v = (s != 0.0f) ? 0.0f : v;                       // hard reset
            }
        }
#pragma unroll
        for (int t = 0; t < 4; ++t) {
            v4f o = { so[t][0], so[t][1], so[t][2], so[t][3] };
            __builtin_nontemporal_store(o, &out4[i + t * NQ4_]);
        }
    }
}

// ---------------------------------------------------------------------------
extern "C" void kernel_launch(void* const* d_in, const int* in_sizes, int n_in,
                              void* d_out, int out_size, void* d_ws, size_t ws_size,
                              hipStream_t stream)
{
    const float* x     = (const float*)d_in[0];   // [4,32,64,4096]
    const float* w     = (const float*)d_in[1];   // [64,64,8]
    // d_in[2] = conv_b: cancels in BN, unused
    const float* gamma = (const float*)d_in[3];   // [64]
    const float* beta  = (const float*)d_in[4];   // [64]
    float* out = (float*)d_out;

    char* ws = (char*)d_ws;
    const size_t y_bytes    = (size_t)TB_ * CO_ * N_ * sizeof(float);   // 128 MB
    const size_t psum_bytes = (size_t)CO_ * 2 * NBLK_ * sizeof(float);  // 1 MB
    float* y    = (float*)ws;
    float* psum = (float*)(ws + y_bytes);
    v2f*   wpk  = (v2f*)(ws + y_bytes + psum_bytes);

    pack_w_kernel<<<64, 256, 0, stream>>>(w, wpk);
    conv_stats_kernel<<<NBLK_, 256, 0, stream>>>(x, wpk, y, psum);
    lif_kernel<<<NBLK_, 256, 0, stream>>>(y, psum, gamma, beta, out);
}